// Round 11
// baseline (279.937 us; speedup 1.0000x reference)
//
#include <hip/hip_runtime.h>
#include <hip/hip_bf16.h>
#include <stdint.h>

#define B_ 4
#define S_ 4096
#define E_ 1024
#define H_ 16
#define D_ 64
#define M_ (B_*S_)          // 16384 rows
constexpr float kEPS = 1e-6f;

typedef unsigned short u16;
typedef unsigned char  u8;
typedef __bf16 bf16x8 __attribute__((ext_vector_type(8)));
typedef float  f32x4  __attribute__((ext_vector_type(4)));
typedef u16    u16x8  __attribute__((ext_vector_type(8)));

typedef const __attribute__((address_space(1))) void* gaddr_t;
typedef __attribute__((address_space(3))) void*       laddr_t;

__device__ __forceinline__ u16 f2bf(float f) {
    union { float f; uint32_t u; } v; v.f = f;
    uint32_t u = v.u;
    u += 0x7fffu + ((u >> 16) & 1u);   // RNE
    return (u16)(u >> 16);
}
__device__ __forceinline__ float hi2f(uint32_t d) {
    union { uint32_t u; float f; } v; v.u = d & 0xffff0000u;
    return v.f;
}
__device__ __forceinline__ float lo2f(uint32_t d) {
    union { uint32_t u; float f; } v; v.u = d << 16;
    return v.f;
}

#define VM_WAIT(n) asm volatile("s_waitcnt vmcnt(" #n ")" ::: "memory")
#define LG0        asm volatile("s_waitcnt lgkmcnt(0)" ::: "memory")
#define SBAR       asm volatile("s_barrier" ::: "memory")

// ---------------- merged f32 -> bf16 conversion: 3 inputs ----------------
__global__ __launch_bounds__(256)
void cvt3_kernel(const float* __restrict__ s0, const float* __restrict__ s1,
                 const float* __restrict__ s2,
                 u16* __restrict__ d0, u16* __restrict__ d1, u16* __restrict__ d2,
                 int n4)
{
    const int z = blockIdx.y;
    const float* src = (z == 0) ? s0 : (z == 1) ? s1 : s2;
    u16*         dst = (z == 0) ? d0 : (z == 1) ? d1 : d2;
    const int stride = gridDim.x * blockDim.x;
    for (int i = blockIdx.x * blockDim.x + threadIdx.x; i < n4; i += stride) {
        float4 v = reinterpret_cast<const float4*>(src)[i];
        ushort4 o;
        o.x = f2bf(v.x); o.y = f2bf(v.y); o.z = f2bf(v.z); o.w = f2bf(v.w);
        reinterpret_cast<ushort4*>(dst)[i] = o;
    }
}

// ---------------- merged weight conversion: 4 weights ----------------
__global__ __launch_bounds__(256)
void cvtw_kernel(const float* __restrict__ w0, const float* __restrict__ w1,
                 const float* __restrict__ w2, const float* __restrict__ w3,
                 u16* __restrict__ o0, u16* __restrict__ o1,
                 u16* __restrict__ o2, u16* __restrict__ o3)
{
    const int z = blockIdx.y;
    const float* src = (z == 0) ? w0 : (z == 1) ? w1 : (z == 2) ? w2 : w3;
    u16*         dst = (z == 0) ? o0 : (z == 1) ? o1 : (z == 2) ? o2 : o3;
    const int i = blockIdx.x * blockDim.x + threadIdx.x;
    float4 v = reinterpret_cast<const float4*>(src)[i];
    ushort4 o;
    o.x = f2bf(v.x); o.y = f2bf(v.y); o.z = f2bf(v.z); o.w = f2bf(v.w);
    reinterpret_cast<ushort4*>(dst)[i] = o;
}

// ================= 256x128 GEMM, BKT=32, 2 blocks/CU (cross-block overlap) =================
// 8 waves of 64x64 output; acc = 64 VGPR -> 4 waves/SIMD; 48 KB LDS -> 2 blocks/CU.
// Per tile: frag ds_reads + stage next tile (3 gload_lds) -> lgkm -> 16 MFMA ->
// vmcnt(0) -> 1 barrier. Per-block drain covered by co-resident block (m114/m97).
// epi: 0 = f32 out + bias; 1 = relu(x+b)+eps -> bf16; 2 = +mask -> bf16 transposed;
//      3 = x+b -> bf16 transposed
#define BM2 256
#define BN2 128
#define BKT2 32
#define NT2 (E_/BKT2)       // 32 K-tiles
// LDS (u16 offsets): buf*12288; A at 0 (8192), B at 8192 (4096). 2 bufs = 49152 B.

struct QKVArgs {
    const u16*   A[3];
    const u16*   W[3];
    const float* bias[3];
    const u8*    mask;
    u16*         C[3];
};

template<bool MERGED>
__global__ __launch_bounds__(512, 4)
void gemm2b(QKVArgs qa,
            const u16* __restrict__ A1, const u16* __restrict__ Bw1,
            const float* __restrict__ bias1, float* __restrict__ Cf)
{
    extern __shared__ u16 lds[];   // 24576 u16 = 48 KB
    const int tid  = threadIdx.x;
    const int wid  = tid >> 6, lane = tid & 63;
    const int wqr  = wid >> 1, wqc = wid & 1;     // 4 x 2 waves of 64x64
    const int m0   = blockIdx.x * BM2;
    const int n0   = blockIdx.y * BN2;
    const int fr   = lane & 15;
    const int cg   = lane >> 4;                   // 0..3 (K=32 as 4 chunks of 8)

    const u16* A;  const u16* Bw;  const float* bias;  u16* Cb;  int epi;
    if constexpr (MERGED) {
        const int z = blockIdx.z;
        A = qa.A[z]; Bw = qa.W[z]; bias = qa.bias[z]; Cb = qa.C[z]; epi = z + 1;
    } else {
        A = A1; Bw = Bw1; bias = bias1; Cb = nullptr; epi = 0;
    }

    // ---- staging geometry: row = tid>>2, stored chunk sc = tid&3;
    //      content chunk ck = sc ^ key(row), key(r) = ((r ^ (r>>2)) & 3)
    const int srow = tid >> 2;                    // 0..127
    const int skey = (srow ^ (srow >> 2)) & 3;
    const int sck  = (tid & 3) ^ skey;
    const u16* aS0 = A  + (size_t)(m0 + srow)*E_        + sck*8;
    const u16* aS1 = A  + (size_t)(m0 + 128 + srow)*E_  + sck*8;   // same key (row+128)
    const u16* bS0 = Bw + (size_t)(n0 + srow)*E_        + sck*8;

    // ---- fragment read offsets (u16; row stride 32) ----
    const int lkey = (fr ^ (fr >> 2)) & 3;
    const int kxr  = (cg ^ lkey) * 8;
    int arow[4], brow[4];
#pragma unroll
    for (int mf = 0; mf < 4; ++mf) arow[mf] = (wqr*64 + mf*16 + fr)*32 + kxr;
#pragma unroll
    for (int nf = 0; nf < 4; ++nf) brow[nf] = 8192 + (wqc*64 + nf*16 + fr)*32 + kxr;

    f32x4 acc[4][4] = {};

    float bias_v[4];
#pragma unroll
    for (int nf = 0; nf < 4; ++nf) bias_v[nf] = bias[n0 + wqc*64 + nf*16 + fr];

#define STAGE(BUF, T) do { \
        const size_t ko_ = (size_t)(T) * BKT2; \
        u16* ab_ = lds + (BUF)*12288; \
        __builtin_amdgcn_global_load_lds((gaddr_t)(aS0 + ko_), (laddr_t)(ab_ + tid*8),          16, 0, 0); \
        __builtin_amdgcn_global_load_lds((gaddr_t)(aS1 + ko_), (laddr_t)(ab_ + (tid+512)*8),    16, 0, 0); \
        __builtin_amdgcn_global_load_lds((gaddr_t)(bS0 + ko_), (laddr_t)(ab_ + 8192 + tid*8),   16, 0, 0); \
    } while (0)

    // ---- prologue ----
    STAGE(0, 0);
    VM_WAIT(0);
    SBAR;
    __builtin_amdgcn_sched_barrier(0);

#pragma unroll 1
    for (int T = 0; T < NT2; ++T) {
        const int cb = T & 1;
        const u16* buf = lds + cb*12288;
        bf16x8 afr[4], bfv[4];
#pragma unroll
        for (int mf = 0; mf < 4; ++mf) afr[mf] = *reinterpret_cast<const bf16x8*>(buf + arow[mf]);
#pragma unroll
        for (int nf = 0; nf < 4; ++nf) bfv[nf] = *reinterpret_cast<const bf16x8*>(buf + brow[nf]);
        if (T < NT2 - 1) STAGE(cb ^ 1, T + 1);
        LG0;
        __builtin_amdgcn_sched_barrier(0);
        __builtin_amdgcn_s_setprio(1);
#pragma unroll
        for (int mf = 0; mf < 4; ++mf)
#pragma unroll
            for (int nf = 0; nf < 4; ++nf)
                acc[mf][nf] = __builtin_amdgcn_mfma_f32_16x16x32_bf16(afr[mf], bfv[nf], acc[mf][nf], 0, 0, 0);
        __builtin_amdgcn_s_setprio(0);
        VM_WAIT(0);
        SBAR;
        __builtin_amdgcn_sched_barrier(0);
    }
#undef STAGE

    // ---- epilogue (runtime epi; wave-uniform branches) ----
    const int bblk = m0 >> 12;
    const int sloc = m0 & 4095;
#pragma unroll
    for (int mf = 0; mf < 4; ++mf) {
#pragma unroll
        for (int nf = 0; nf < 4; ++nf) {
            const int gn = n0 + wqc*64 + nf*16 + fr;
            const int mb = wqr*64 + mf*16 + cg*4;
            if (epi >= 2) {
                ushort4 o;
#pragma unroll
                for (int r = 0; r < 4; ++r) {
                    float x = acc[mf][nf][r] + bias_v[nf];
                    if (epi == 2) {
                        x = fmaxf(x, 0.f) + kEPS;
                        if (qa.mask[m0 + mb + r]) x = 0.f;
                    }
                    ((u16*)&o)[r] = f2bf(x);
                }
                *reinterpret_cast<ushort4*>(Cb + ((size_t)(bblk*1024 + gn))*4096 + sloc + mb) = o;
            } else if (epi == 1) {
#pragma unroll
                for (int r = 0; r < 4; ++r) {
                    const int gm = m0 + mb + r;
                    float x = acc[mf][nf][r] + bias_v[nf];
                    x = fmaxf(x, 0.f) + kEPS;
                    Cb[(size_t)gm*E_ + gn] = f2bf(x);
                }
            } else {
#pragma unroll
                for (int r = 0; r < 4; ++r) {
                    const int gm = m0 + mb + r;
                    Cf[(size_t)gm*E_ + gn] = acc[mf][nf][r] + bias_v[nf];
                }
            }
        }
    }
}

// ---- kv_context via MFMA: kvT[v][d] = sum_s VvT[v][s] * KaT[d][s] ----
#define NSC 8
#define KCH (S_/NSC)       // 512 s per block
__global__ __launch_bounds__(256)
void kv_mfma_kernel(const u16* __restrict__ KaT, const u16* __restrict__ VvT,
                    float* __restrict__ kvp, float* __restrict__ ksp)
{
    __shared__ float sm[4][64];
    const int bh = blockIdx.x, sc = blockIdx.y;
    const int tid = threadIdx.x;
    const int w = tid >> 6, lane = tid & 63;
    const int fr = lane & 15, cg = lane >> 4;

    const u16* Ar = VvT + ((size_t)bh*64 + w*16 + fr)*4096 + sc*KCH;
    const u16* Br0 = KaT + ((size_t)bh*64 + fr)*4096 + sc*KCH;

    f32x4 acc[4] = {};
#pragma unroll 2
    for (int ks = 0; ks < KCH/32; ++ks) {
        const int ko = ks*32 + cg*8;
        bf16x8 af = *reinterpret_cast<const bf16x8*>(Ar + ko);
#pragma unroll
        for (int nf = 0; nf < 4; ++nf) {
            bf16x8 bf = *reinterpret_cast<const bf16x8*>(Br0 + (size_t)nf*16*4096 + ko);
            acc[nf] = __builtin_amdgcn_mfma_f32_16x16x32_bf16(af, bf, acc[nf], 0, 0, 0);
        }
    }
    float* dst = kvp + ((size_t)sc*64 + bh)*4096;
#pragma unroll
    for (int nf = 0; nf < 4; ++nf)
#pragma unroll
        for (int r = 0; r < 4; ++r)
            dst[(w*16 + cg*4 + r)*64 + nf*16 + fr] = acc[nf][r];

    {
        const int d = tid & 63, qq = tid >> 6;
        const u16* kr = KaT + ((size_t)bh*64 + d)*4096 + sc*KCH + qq*(KCH/4);
        float s = 0.f;
#pragma unroll 4
        for (int i = 0; i < KCH/4/8; ++i) {
            bf16x8 kk = *reinterpret_cast<const bf16x8*>(kr + i*8);
#pragma unroll
            for (int j = 0; j < 8; ++j) s += (float)kk[j];
        }
        sm[qq][d] = s;
    }
    __syncthreads();
    if (tid < 64)
        ksp[((size_t)sc*64 + bh)*64 + tid] = sm[0][tid] + sm[1][tid] + sm[2][tid] + sm[3][tid];
}

// ---- reduce partials: kvT bf16 [bh][v][d] + ksum ----
__global__ __launch_bounds__(256)
void kv_reduce_kernel(const float* __restrict__ kvp, const float* __restrict__ ksp,
                      u16* __restrict__ kvT, float* __restrict__ ksum)
{
    const int i = blockIdx.x*256 + threadIdx.x;   // 262144
    float s = 0.f;
#pragma unroll
    for (int c = 0; c < NSC; ++c) s += kvp[(size_t)c*262144 + i];
    kvT[i] = f2bf(s);
    if (i < 4096) {
        float t = 0.f;
#pragma unroll
        for (int c = 0; c < NSC; ++c) t += ksp[(size_t)c*4096 + i];
        ksum[i] = t;
    }
}

// ---------------- stage 3: attn = (Qa @ kv) / max(Qa . ksum, eps), MFMA ----------------
__global__ __launch_bounds__(256)
void attn_kernel(const u16* __restrict__ Qa, const u16* __restrict__ kvT,
                 const float* __restrict__ ksum, u16* __restrict__ attn)
{
    __shared__ u16  Qs[256*64];
    __shared__ u16  Ts[64*64];
    __shared__ float kss[64];
    __shared__ float invd[256];

    const int bh = blockIdx.x, b = bh >> 4, h = bh & 15;
    const int s0 = blockIdx.y * 256;
    const int tid = threadIdx.x;
    const int wid = tid >> 6, lane = tid & 63;
    const int fr = lane & 15, cg = lane >> 4;

#pragma unroll
    for (int j = 0; j < 8; ++j) {
        int L = (wid*8 + j)*64 + lane;
        int row = L >> 3, c = L & 7;
        int cs = c ^ (row & 7);
        const u16* src = Qa + (size_t)(b*S_ + s0 + row)*E_ + h*64 + cs*8;
        __builtin_amdgcn_global_load_lds((gaddr_t)src, (laddr_t)(Qs + L*8), 16, 0, 0);
    }
#pragma unroll
    for (int k = 0; k < 2; ++k) {
        int g = k*256 + tid;
        int v = g >> 3, c = g & 7;
        uint4 q = *reinterpret_cast<const uint4*>(kvT + (size_t)bh*4096 + g*8);
        int cs = c ^ (v & 7);
        *reinterpret_cast<uint4*>(Ts + v*64 + cs*8) = q;
    }
    if (tid < 64) kss[tid] = ksum[bh*64 + tid];
    asm volatile("s_waitcnt vmcnt(0) lgkmcnt(0)" ::: "memory");
    __syncthreads();

    {
        float den = 0.f;
#pragma unroll
        for (int c = 0; c < 8; ++c) {
            uint4 qc = *reinterpret_cast<const uint4*>(Qs + tid*64 + (c ^ (tid & 7))*8);
            den += lo2f(qc.x)*kss[c*8+0] + hi2f(qc.x)*kss[c*8+1]
                 + lo2f(qc.y)*kss[c*8+2] + hi2f(qc.y)*kss[c*8+3]
                 + lo2f(qc.z)*kss[c*8+4] + hi2f(qc.z)*kss[c*8+5]
                 + lo2f(qc.w)*kss[c*8+6] + hi2f(qc.w)*kss[c*8+7];
        }
        invd[tid] = 1.0f / fmaxf(den, kEPS);
    }
    __syncthreads();

    f32x4 acc[4][4] = {};
#pragma unroll
    for (int ks = 0; ks < 2; ++ks) {
        bf16x8 bfrag[4];
#pragma unroll
        for (int nf = 0; nf < 4; ++nf) {
            int v = nf*16 + fr;
            bfrag[nf] = *reinterpret_cast<const bf16x8*>(Ts + v*64 + ((ks*4 + cg) ^ (v & 7))*8);
        }
#pragma unroll
        for (int mf = 0; mf < 4; ++mf) {
            int m = wid*64 + mf*16 + fr;
            bf16x8 afrag = *reinterpret_cast<const bf16x8*>(Qs + m*64 + ((ks*4 + cg) ^ (m & 7))*8);
#pragma unroll
            for (int nf = 0; nf < 4; ++nf)
                acc[mf][nf] = __builtin_amdgcn_mfma_f32_16x16x32_bf16(afrag, bfrag[nf], acc[mf][nf], 0, 0, 0);
        }
    }

#pragma unroll
    for (int mf = 0; mf < 4; ++mf) {
#pragma unroll
        for (int nf = 0; nf < 4; ++nf) {
            const int v = nf*16 + fr;
#pragma unroll
            for (int r = 0; r < 4; ++r) {
                const int row = wid*64 + mf*16 + cg*4 + r;
                float x = acc[mf][nf][r] * invd[row];
                attn[(size_t)(b*S_ + s0 + row)*E_ + h*64 + v] = f2bf(x);
            }
        }
    }
}

// ---------------- host ----------------
extern "C" void kernel_launch(void* const* d_in, const int* in_sizes, int n_in,
                              void* d_out, int out_size, void* d_ws, size_t ws_size,
                              hipStream_t stream)
{
    const float* query = (const float*)d_in[0];
    const float* key   = (const float*)d_in[1];
    const float* value = (const float*)d_in[2];
    const u8*    mask  = (const u8*)d_in[3];
    const float* Wq = (const float*)d_in[4];
    const float* bq = (const float*)d_in[5];
    const float* Wk = (const float*)d_in[6];
    const float* bk = (const float*)d_in[7];
    const float* Wv = (const float*)d_in[8];
    const float* bv = (const float*)d_in[9];
    const float* Wo = (const float*)d_in[10];
    const float* bo = (const float*)d_in[11];
    float* out = (float*)d_out;

    const size_t SZ_ME = (size_t)M_ * E_;
    const size_t SZ_EE = (size_t)E_ * E_;

    char* ws = (char*)d_ws;
    u16* qx   = (u16*)ws; ws += SZ_ME*2;   // query bf16; reused later for attnb
    u16* kx   = (u16*)ws; ws += SZ_ME*2;   // key bf16
    u16* vx   = (u16*)ws; ws += SZ_ME*2;   // value bf16
    u16* Qa   = (u16*)ws; ws += SZ_ME*2;
    u16* KaT  = (u16*)ws; ws += SZ_ME*2;   // [b*1024+h*64+d][4096] bf16
    u16* VvT  = (u16*)ws; ws += SZ_ME*2;   // [b*1024+h*64+v][4096] bf16
    u16* wqb  = (u16*)ws; ws += SZ_EE*2;
    u16* wkb  = (u16*)ws; ws += SZ_EE*2;
    u16* wvb  = (u16*)ws; ws += SZ_EE*2;
    u16* wob  = (u16*)ws; ws += SZ_EE*2;
    float* kvp = (float*)ws; ws += (size_t)NSC*64*4096*4;   // 8 MiB
    float* ksp = (float*)ws; ws += (size_t)NSC*4096*4;      // 128 KiB
    u16*  kvT  = (u16*)ws;  ws += (size_t)64*4096*2;        // 512 KiB
    float* ksum= (float*)ws; ws += 4096*4;

    u16* attnb = qx;   // overlay: qx dead after QKV gemm consumes it

    // 1) conversions to bf16 (2 dispatches)
    cvt3_kernel<<<dim3(2048, 3), 256, 0, stream>>>(query, key, value, qx, kx, vx, (int)(SZ_ME/4));
    cvtw_kernel<<<dim3(1024, 4), 256, 0, stream>>>(Wq, Wk, Wv, Wo, wqb, wkb, wvb, wob);

    // 2) QKV projections: ONE dispatch, grid.z selects projection
    QKVArgs qa;
    qa.A[0] = qx;  qa.A[1] = kx;  qa.A[2] = vx;
    qa.W[0] = wqb; qa.W[1] = wkb; qa.W[2] = wvb;
    qa.bias[0] = bq; qa.bias[1] = bk; qa.bias[2] = bv;
    qa.mask = mask;
    qa.C[0] = Qa; qa.C[1] = KaT; qa.C[2] = VvT;
    dim3 ggrid(M_/BM2, E_/BN2, 3);    // (64, 8, 3)
    constexpr size_t LDS_BYTES = 2 * 12288 * sizeof(u16);   // 48 KB
    gemm2b<true><<<ggrid, 512, LDS_BYTES, stream>>>(qa, nullptr, nullptr, nullptr, nullptr);

    // 3) kv_context + k_sum via MFMA (two-phase, deterministic)
    kv_mfma_kernel<<<dim3(64, NSC), 256, 0, stream>>>(KaT, VvT, kvp, ksp);
    kv_reduce_kernel<<<1024, 256, 0, stream>>>(kvp, ksp, kvT, ksum);

    // 4) attn numerator / denom (MFMA) -> attnb
    attn_kernel<<<dim3(B_*H_, S_/256), 256, 0, stream>>>(Qa, kvT, ksum, attnb);

    // 5) output projection -> f32 out
    QKVArgs dummy = {};
    dummy.mask = mask;
    gemm2b<false><<<dim3(M_/BM2, E_/BN2, 1), 512, LDS_BYTES, stream>>>(dummy, attnb, wob, bo, out);
}